// Round 3
// baseline (436.198 us; speedup 1.0000x reference)
//
#include <hip/hip_runtime.h>
#include <math.h>

// Problem constants (match reference)
#define N_RAYS    131072
#define N_SAMPLES 128
#define BIG_DIST  1e10f
#define EPS       1e-10f

// Output layout (flat concat, all fp32):
//   rgb_map   [R,3]   offset 0
//   disp_map  [R]     offset 393216
//   acc_map   [R]     offset 524288
//   weights   [R,S]   offset 655360
//   depth_map [R]     offset 17432576
#define OFF_RGB    0
#define OFF_DISP   393216
#define OFF_ACC    524288
#define OFF_W      655360
#define OFF_DEPTH  17432576

#define NWAVES        8192                    // 2048 blocks x 4 waves (~32 waves/CU)
#define RAYS_PER_WAVE (N_RAYS / NWAVES)       // 16

// One wave per ray-slice; lane L owns samples {L, 64+L} (unit-stride loads).
// Persistent waves: each wave processes 16 rays, double-buffered prefetch.
__global__ __launch_bounds__(256) void nerf_render_persist(
    const float4* __restrict__ raw,     // [R, S] rgb+sigma
    const float*  __restrict__ z_vals,  // [R, S]
    const float*  __restrict__ rays_d,  // [R, 3]
    float* __restrict__ out)
{
    const int wid  = (blockIdx.x * blockDim.x + threadIdx.x) >> 6;
    const int lane = threadIdx.x & 63;

    float4 rvA[2], rvB[2];
    float  zA[2],  zB[2];
    float  rdx[2], rdy[2], rdz[2];

    // prefetch iteration 0's ray
    {
        const int r = wid;
        const float4* rawr = raw + (size_t)r * N_SAMPLES;
        rvA[0] = rawr[lane];
        rvB[0] = rawr[64 + lane];
        const float* zr = z_vals + (size_t)r * N_SAMPLES;
        zA[0] = zr[lane];
        zB[0] = zr[64 + lane];
        const int ru = __builtin_amdgcn_readfirstlane(r);
        rdx[0] = rays_d[3 * ru + 0];
        rdy[0] = rays_d[3 * ru + 1];
        rdz[0] = rays_d[3 * ru + 2];
    }

#pragma unroll 2
    for (int i = 0; i < RAYS_PER_WAVE; ++i) {
        const int cur = i & 1;
        const int nxt = cur ^ 1;

        // ---- prefetch next ray (issues before this ray's vmcnt waits) ----
        if (i + 1 < RAYS_PER_WAVE) {
            const int rn = wid + (i + 1) * NWAVES;
            const float4* rawr = raw + (size_t)rn * N_SAMPLES;
            rvA[nxt] = rawr[lane];
            rvB[nxt] = rawr[64 + lane];
            const float* zr = z_vals + (size_t)rn * N_SAMPLES;
            zA[nxt] = zr[lane];
            zB[nxt] = zr[64 + lane];
            const int ru = __builtin_amdgcn_readfirstlane(rn);
            rdx[nxt] = rays_d[3 * ru + 0];
            rdy[nxt] = rays_d[3 * ru + 1];
            rdz[nxt] = rays_d[3 * ru + 2];
        }

        // ---- compute current ray ----
        const int r = wid + i * NWAVES;
        const float4 ra = rvA[cur];
        const float4 rb = rvB[cur];
        const float  za = zA[cur];
        const float  zb = zB[cur];
        const float  dxx = rdx[cur], dyy = rdy[cur], dzz = rdz[cur];
        const float  nrm = sqrtf(dxx * dxx + dyy * dyy + dzz * dzz);

        // neighbor z values for interval lengths
        const float zsA = __shfl_down(za, 1);   // z[lane+1]      (lane<63)
        const float zb0 = __shfl(zb, 0);        // z[64]
        const float zsB = __shfl_down(zb, 1);   // z[64+lane+1]   (lane<63)
        const float znA = (lane == 63) ? zb0 : zsA;

        const float distA = (znA - za) * nrm;
        const float distB = (lane == 63) ? (BIG_DIST * nrm) : ((zsB - zb) * nrm);

        const float sigA = fmaxf(ra.w, 0.0f);
        const float sigB = fmaxf(rb.w, 0.0f);
        const float aA = 1.0f - __expf(-sigA * distA);
        const float aB = 1.0f - __expf(-sigB * distB);
        const float fA = 1.0f - aA + EPS;
        const float fB = 1.0f - aB + EPS;

        // two interleaved 64-lane inclusive prefix products (independent chains)
        float sA = fA, sB = fB;
#pragma unroll
        for (int off = 1; off < 64; off <<= 1) {
            const float tA = __shfl_up(sA, off);
            const float tB = __shfl_up(sB, off);
            if (lane >= off) { sA *= tA; sB *= tB; }
        }
        float TA  = __shfl_up(sA, 1); if (lane == 0) TA  = 1.0f;  // excl prefix, half A
        float TBe = __shfl_up(sB, 1); if (lane == 0) TBe = 1.0f;  // excl prefix, half B
        const float Ph = __shfl(sA, 63);                          // product of half A
        const float TB = Ph * TBe;

        const float wA = aA * TA;
        const float wB = aB * TB;

        // weights store: two unit-stride dword stores (256 B each per wave)
        float* wout = out + OFF_W + (size_t)r * N_SAMPLES;
        wout[lane]      = wA;
        wout[64 + lane] = wB;

        // sigmoid(rgb)
        const float srA = __builtin_amdgcn_rcpf(1.0f + __expf(-ra.x));
        const float sgA = __builtin_amdgcn_rcpf(1.0f + __expf(-ra.y));
        const float sbA = __builtin_amdgcn_rcpf(1.0f + __expf(-ra.z));
        const float srB = __builtin_amdgcn_rcpf(1.0f + __expf(-rb.x));
        const float sgB = __builtin_amdgcn_rcpf(1.0f + __expf(-rb.y));
        const float sbB = __builtin_amdgcn_rcpf(1.0f + __expf(-rb.z));

        float cr    = wA * srA + wB * srB;
        float cg    = wA * sgA + wB * sgB;
        float cb    = wA * sbA + wB * sbB;
        float depth = wA * za  + wB * zb;
        float acc   = wA + wB;

        // butterfly reduction, 5 independent chains
#pragma unroll
        for (int m = 32; m > 0; m >>= 1) {
            cr    += __shfl_xor(cr, m);
            cg    += __shfl_xor(cg, m);
            cb    += __shfl_xor(cb, m);
            depth += __shfl_xor(depth, m);
            acc   += __shfl_xor(acc, m);
        }

        if (lane == 0) {
            out[OFF_RGB + 3 * r + 0] = cr;
            out[OFF_RGB + 3 * r + 1] = cg;
            out[OFF_RGB + 3 * r + 2] = cb;
            out[OFF_ACC + r]   = acc;
            out[OFF_DEPTH + r] = depth;
            out[OFF_DISP + r]  = 1.0f / fmaxf(EPS, depth / acc);
        }
    }
}

extern "C" void kernel_launch(void* const* d_in, const int* in_sizes, int n_in,
                              void* d_out, int out_size, void* d_ws, size_t ws_size,
                              hipStream_t stream) {
    const float4* raw    = (const float4*)d_in[0];
    const float*  z_vals = (const float*)d_in[1];
    const float*  rays_d = (const float*)d_in[2];
    float* out = (float*)d_out;

    const int block = 256;                     // 4 waves per block
    const int grid  = NWAVES * 64 / block;     // 2048 blocks
    nerf_render_persist<<<grid, block, 0, stream>>>(raw, z_vals, rays_d, out);
}

// Round 4
// 415.029 us; speedup vs baseline: 1.0510x; 1.0510x over previous
//
#include <hip/hip_runtime.h>
#include <math.h>

// Problem constants (match reference)
#define N_RAYS    131072
#define N_SAMPLES 128
#define BIG_DIST  1e10f
#define EPS       1e-10f

// Output layout (flat concat, all fp32):
//   rgb_map   [R,3]   offset 0
//   disp_map  [R]     offset 393216
//   acc_map   [R]     offset 524288
//   weights   [R,S]   offset 655360
//   depth_map [R]     offset 17432576
#define OFF_RGB    0
#define OFF_DISP   393216
#define OFF_ACC    524288
#define OFF_W      655360
#define OFF_DEPTH  17432576

#define RPW 4   // rays per wave, all loads issued up-front (no loop carry)

// Lane L owns samples {2L, 2L+1} of each of its wave's 4 rays.
// Exclusive transmittance cumprod via one 6-step prefix-product scan per ray;
// the 4 rays' scans/reductions interleave to pipeline the DS unit.
__global__ __launch_bounds__(256) void nerf_render_ilp4(
    const float4* __restrict__ raw,     // [R, S] rgb+sigma
    const float*  __restrict__ z_vals,  // [R, S]
    const float*  __restrict__ rays_d,  // [R, 3]
    float* __restrict__ out)
{
    const int wid   = (blockIdx.x * blockDim.x + threadIdx.x) >> 6;
    const int lane  = threadIdx.x & 63;
    const int rbase = wid * RPW;

    // ---- issue ALL loads first (≈10 KB in flight per wave) ----
    float4 rv0[RPW], rv1[RPW];
    float2 z[RPW];
#pragma unroll
    for (int k = 0; k < RPW; ++k) {
        const size_t r = rbase + k;
        const float4* rawr = raw + r * N_SAMPLES;
        rv0[k] = rawr[2 * lane];
        rv1[k] = rawr[2 * lane + 1];
        z[k]   = ((const float2*)(z_vals + r * N_SAMPLES))[lane];
    }
    float nrm[RPW];
#pragma unroll
    for (int k = 0; k < RPW; ++k) {
        const int r = rbase + k;           // wave-uniform
        const float dxx = rays_d[3 * r + 0];
        const float dyy = rays_d[3 * r + 1];
        const float dzz = rays_d[3 * r + 2];
        nrm[k] = sqrtf(dxx * dxx + dyy * dyy + dzz * dzz);
    }

    // ---- per-sample alpha & per-lane transmittance factor ----
    float a0[RPW], a1[RPW], f0[RPW], sp[RPW];
#pragma unroll
    for (int k = 0; k < RPW; ++k) {
        const float znext = __shfl_down(z[k].x, 1);      // z[2L+2]
        const float dist0 = (z[k].y - z[k].x) * nrm[k];
        const float dist1 = (lane == 63) ? (BIG_DIST * nrm[k])
                                         : ((znext - z[k].y) * nrm[k]);
        const float sig0 = fmaxf(rv0[k].w, 0.0f);
        const float sig1 = fmaxf(rv1[k].w, 0.0f);
        a0[k] = 1.0f - __expf(-sig0 * dist0);
        a1[k] = 1.0f - __expf(-sig1 * dist1);
        f0[k] = 1.0f - a0[k] + EPS;
        const float f1 = 1.0f - a1[k] + EPS;
        sp[k] = f0[k] * f1;                               // per-lane product
    }

    // ---- 4 interleaved inclusive prefix-product scans (6 stages) ----
#pragma unroll
    for (int off = 1; off < 64; off <<= 1) {
        float t[RPW];
#pragma unroll
        for (int k = 0; k < RPW; ++k) t[k] = __shfl_up(sp[k], off);
#pragma unroll
        for (int k = 0; k < RPW; ++k) if (lane >= off) sp[k] *= t[k];
    }

    // ---- weights + per-lane reduction partials ----
    float cr[RPW], cg[RPW], cb[RPW], depth[RPW], acc[RPW];
#pragma unroll
    for (int k = 0; k < RPW; ++k) {
        float Texc = __shfl_up(sp[k], 1);
        if (lane == 0) Texc = 1.0f;
        const float T0 = Texc;
        const float T1 = Texc * f0[k];
        const float w0 = a0[k] * T0;
        const float w1 = a1[k] * T1;

        const size_t r = rbase + k;
        ((float2*)(out + OFF_W + r * N_SAMPLES))[lane] = make_float2(w0, w1);

        const float sr0 = __builtin_amdgcn_rcpf(1.0f + __expf(-rv0[k].x));
        const float sg0 = __builtin_amdgcn_rcpf(1.0f + __expf(-rv0[k].y));
        const float sb0 = __builtin_amdgcn_rcpf(1.0f + __expf(-rv0[k].z));
        const float sr1 = __builtin_amdgcn_rcpf(1.0f + __expf(-rv1[k].x));
        const float sg1 = __builtin_amdgcn_rcpf(1.0f + __expf(-rv1[k].y));
        const float sb1 = __builtin_amdgcn_rcpf(1.0f + __expf(-rv1[k].z));

        cr[k]    = w0 * sr0 + w1 * sr1;
        cg[k]    = w0 * sg0 + w1 * sg1;
        cb[k]    = w0 * sb0 + w1 * sb1;
        depth[k] = w0 * z[k].x + w1 * z[k].y;
        acc[k]   = w0 + w1;
    }

    // ---- interleaved butterfly reductions (20 independent chains) ----
#pragma unroll
    for (int m = 32; m > 0; m >>= 1) {
#pragma unroll
        for (int k = 0; k < RPW; ++k) {
            cr[k]    += __shfl_xor(cr[k], m);
            cg[k]    += __shfl_xor(cg[k], m);
            cb[k]    += __shfl_xor(cb[k], m);
            depth[k] += __shfl_xor(depth[k], m);
            acc[k]   += __shfl_xor(acc[k], m);
        }
    }

    if (lane == 0) {
#pragma unroll
        for (int k = 0; k < RPW; ++k) {
            const size_t r = rbase + k;
            out[OFF_RGB + 3 * r + 0] = cr[k];
            out[OFF_RGB + 3 * r + 1] = cg[k];
            out[OFF_RGB + 3 * r + 2] = cb[k];
            out[OFF_ACC + r]   = acc[k];
            out[OFF_DEPTH + r] = depth[k];
            out[OFF_DISP + r]  = 1.0f / fmaxf(EPS, depth[k] / acc[k]);
        }
    }
}

extern "C" void kernel_launch(void* const* d_in, const int* in_sizes, int n_in,
                              void* d_out, int out_size, void* d_ws, size_t ws_size,
                              hipStream_t stream) {
    const float4* raw    = (const float4*)d_in[0];
    const float*  z_vals = (const float*)d_in[1];
    const float*  rays_d = (const float*)d_in[2];
    float* out = (float*)d_out;

    const int block = 256;                              // 4 waves/block
    const int waves = N_RAYS / RPW;                     // 32768
    const int grid  = waves * 64 / block;               // 8192 blocks
    nerf_render_ilp4<<<grid, block, 0, stream>>>(raw, z_vals, rays_d, out);
}